// Round 5
// baseline (98.281 us; speedup 1.0000x reference)
//
#include <hip/hip_runtime.h>

#define NBINS 4352                 // bin = float_bits(d)>>18 ; d<=~4 -> bin<=4128
#define ACC_OFF (3 * NBINS)        // word offset of per-layer n^2 accumulators in ws

typedef float    f4v __attribute__((ext_vector_type(4)));
typedef _Float16 h4v __attribute__((ext_vector_type(4)));

// ---- t/s block: 8192 t-elems + 8192 s-elems (P positions x C channels), one
// batch image. Every thread: 8 channels x 4 consecutive positions. All 16
// float4 loads issued before first use; t,s retained as f16 while f32 norms
// reduce through LDS; then register-only d histogram (no global re-read). ----
template<int C, int HWSHIFT, int PSHIFT, int LAYER>
__device__ __forceinline__ void ts_block(
    const float* __restrict__ t, const float* __restrict__ s,
    int lb, unsigned int* __restrict__ ws_u,
    unsigned int* cnt_sh, float* ov_sh, float* inv_sh)
{
    const int HW  = 1 << HWSHIFT;
    const int P   = 1 << PSHIFT;        // positions per block: 32/64/128
    const int NPQ = P >> 2;             // position-quads per wave
    const int G   = 1024 >> PSHIFT;     // norm partials per position: 32/16/8
    const int tid = threadIdx.x;
    const int w   = tid >> 6;
    const int l   = tid & 63;
    const int pq  = l & (NPQ - 1);      // which position-quad
    const int cs  = l >> (PSHIFT - 2);  // channel sub-group within wave

    const int p0 = lb << PSHIFT;        // first flat position (never straddles b)
    const int b  = p0 >> HWSHIFT;
    const int q  = p0 & (HW - 1);
    const int c0 = w * (C / 4) + cs * 8;
    const size_t base = ((size_t)(b * C + c0) << HWSHIFT) + q + 4 * pq;
    const float* tp = t + base;
    const float* sp = s + base;

    // ---- issue all 16 loads up-front (forced MLP) ----
    f4v tt[8], ss[8];
    #pragma unroll
    for (int k = 0; k < 8; ++k) {
        const size_t o = (size_t)k << HWSHIFT;
        tt[k] = *(const f4v*)(tp + o);
        ss[k] = *(const f4v*)(sp + o);
    }

    // zero histogram while loads are in flight (separate LDS buffer)
    for (int i = tid; i < NBINS / 4; i += 256)
        ((uint4*)cnt_sh)[i] = make_uint4(0u, 0u, 0u, 0u);

    // ---- f32 norm partials + f16 retain ----
    f4v accT = {0.f,0.f,0.f,0.f}, accS = {0.f,0.f,0.f,0.f};
    h4v th[8], sh[8];
    #pragma unroll
    for (int k = 0; k < 8; ++k) {
        accT += tt[k] * tt[k];
        accS += ss[k] * ss[k];
        th[k] = (h4v){(_Float16)tt[k].x, (_Float16)tt[k].y,
                      (_Float16)tt[k].z, (_Float16)tt[k].w};
        sh[k] = (h4v){(_Float16)ss[k].x, (_Float16)ss[k].y,
                      (_Float16)ss[k].z, (_Float16)ss[k].w};
    }
    const int g_id = w * (64 / NPQ) + cs;          // 0..G-1
    ((f4v*)ov_sh)[g_id * NPQ + pq]          = accT;   // ovT: [G][P] floats
    ((f4v*)(ov_sh + 1024))[g_id * NPQ + pq] = accS;   // ovS: [G][P] floats
    __syncthreads();

    // ---- per-position inv norms ----
    if (tid < 2 * P) {
        const int pos = tid & (P - 1);
        const float* src = ov_sh + (tid < P ? 0 : 1024);
        float acc = 0.f;
        #pragma unroll
        for (int gg = 0; gg < G; ++gg) acc += src[gg * P + pos];
        inv_sh[tid] = 1.0f / fmaxf(sqrtf(acc), 1e-12f);  // [0,P)=T, [P,2P)=S
    }
    __syncthreads();

    // ---- register-only pass 2: d = (t*invT - s*invS)^2, count histogram ----
    f4v iT = ((const f4v*)inv_sh)[pq];
    f4v iS = ((const f4v*)inv_sh)[NPQ + pq];
    #pragma unroll
    for (int k = 0; k < 8; ++k) {
        f4v tv = {(float)th[k].x, (float)th[k].y, (float)th[k].z, (float)th[k].w};
        f4v sv = {(float)sh[k].x, (float)sh[k].y, (float)sh[k].z, (float)sh[k].w};
        f4v a  = tv * iT - sv * iS;
        f4v d  = a * a;
        atomicAdd(&cnt_sh[min(__float_as_uint(d.x) >> 18, (unsigned)(NBINS-1))], 1u);
        atomicAdd(&cnt_sh[min(__float_as_uint(d.y) >> 18, (unsigned)(NBINS-1))], 1u);
        atomicAdd(&cnt_sh[min(__float_as_uint(d.z) >> 18, (unsigned)(NBINS-1))], 1u);
        atomicAdd(&cnt_sh[min(__float_as_uint(d.w) >> 18, (unsigned)(NBINS-1))], 1u);
    }
    __syncthreads();

    // ---- flush nonzero bins to global per-layer histogram ----
    unsigned int* gc = ws_u + LAYER * NBINS;
    for (int i = tid; i < NBINS; i += 256) {
        unsigned c = cnt_sh[i];
        if (c) atomicAdd(&gc[i], c);
    }
}

// ---- n block: barrier-free streaming sum of squares over 8192 float4s ----
__device__ __forceinline__ void n_block(
    const float* __restrict__ n, int layer, int lb, float* __restrict__ ws_f)
{
    const f4v* p = (const f4v*)n + ((size_t)lb << 13) + threadIdx.x;
    float a = 0.f;
    #pragma unroll 8
    for (int i = 0; i < 32; ++i) {
        f4v v = p[i * 256];
        a += v.x*v.x + v.y*v.y + v.z*v.z + v.w*v.w;
    }
    #pragma unroll
    for (int o = 32; o > 0; o >>= 1) a += __shfl_down(a, o, 64);
    if ((threadIdx.x & 63) == 0) atomicAdd(&ws_f[ACC_OFF + layer], a);
}

// Grid: 4480 blocks, interleaved 4 ts : 1 n per group of 5.
// ts order: 512 (layer2) + 1024 (layer1) + 2048 (layer0).
// n  order: 128 (n2) + 256 (n1) + 512 (n0).
__global__ __launch_bounds__(256, 4) void stfpm_main(
    const float* __restrict__ t0, const float* __restrict__ s0, const float* __restrict__ n0,
    const float* __restrict__ t1, const float* __restrict__ s1, const float* __restrict__ n1,
    const float* __restrict__ t2, const float* __restrict__ s2, const float* __restrict__ n2,
    unsigned int* __restrict__ ws_u, float* __restrict__ ws_f)
{
    __shared__ __align__(16) unsigned int cnt_sh[NBINS];  // 17 KB
    __shared__ __align__(16) float ov_sh[2048];           // 8 KB reduce overlay
    __shared__ __align__(16) float inv_sh[256];           // 1 KB
    const int bid = blockIdx.x;
    const int g = bid / 5;
    const int r = bid - g * 5;
    if (r == 4) {
        if (g < 128)      n_block(n2, 2, g,       ws_f);
        else if (g < 384) n_block(n1, 1, g - 128, ws_f);
        else              n_block(n0, 0, g - 384, ws_f);
        return;
    }
    const int ts = g * 4 + r;
    if (ts < 512)
        ts_block<256, 10, 5, 2>(t2, s2, ts,        ws_u, cnt_sh, ov_sh, inv_sh);
    else if (ts < 1536)
        ts_block<128, 12, 6, 1>(t1, s1, ts - 512,  ws_u, cnt_sh, ov_sh, inv_sh);
    else
        ts_block<64,  14, 7, 0>(t0, s0, ts - 1536, ws_u, cnt_sh, ov_sh, inv_sh);
}

__device__ __forceinline__ float bin_mid(int b) {
    float lo = __uint_as_float((unsigned)b << 18);
    float hi = __uint_as_float((unsigned)(b + 1) << 18);
    return 0.5f * (lo + hi);
}

// Single block: per layer, scan counts from the top; full bins above the
// boundary contribute cnt * bin-midpoint; boundary bin uses the uniform-
// within-bin model for its top-j elements. Adds mean(n^2); writes the scalar.
__global__ __launch_bounds__(256) void stfpm_finalize(
    const unsigned int* __restrict__ ws_u, const float* __restrict__ ws_f,
    float* __restrict__ out)
{
    __shared__ unsigned int cchunk[256];
    __shared__ float        schunk[256];
    const int tid = threadIdx.x;

    const int   targets[3] = {16778, 8389, 4195};  // cnt = N-1-floor(0.999(N-1))
    const float Ns[3]      = {16777216.f, 8388608.f, 4194304.f};
    const int   CHUNK = NBINS / 256;  // 17

    float total = 0.f;  // thread 0 only
    for (int layer = 0; layer < 3; ++layer) {
        const unsigned int* gc = ws_u + layer * NBINS;
        unsigned int c = 0; float sv = 0.f;
        const int b0 = tid * CHUNK;
        for (int i = 0; i < CHUNK; ++i) {
            unsigned cc = gc[b0 + i];
            c += cc;
            if (cc) sv += (float)cc * bin_mid(b0 + i);
        }
        __syncthreads();
        cchunk[tid] = c; schunk[tid] = sv;
        __syncthreads();
        if (tid == 0) {
            const int target = targets[layer];
            long long cum = 0; float sAbove = 0.f;
            int ch = 255;
            while (ch >= 0 && cum + (long long)cchunk[ch] < target) {
                cum += cchunk[ch]; sAbove += schunk[ch]; --ch;
            }
            int bin = ch * CHUNK + CHUNK - 1;
            while (bin >= ch * CHUNK && cum + (long long)gc[bin] < target) {
                unsigned cc = gc[bin];
                cum += cc; sAbove += (float)cc * bin_mid(bin); --bin;
            }
            unsigned cb = gc[bin];          // boundary bin count (>=1)
            int j = target - (int)cum;      // elements taken from boundary bin
            float lo = __uint_as_float((unsigned)bin << 18);
            float hi = __uint_as_float((unsigned)(bin + 1) << 18);
            float wd = hi - lo;
            float f  = (float)j / (float)cb;
            float topmean = hi - f * wd * 0.5f;  // mean of top-j under uniform model
            topmean = fminf(fmaxf(topmean, lo), hi);
            float hard   = (sAbove + topmean * (float)j) / (float)target;
            float n2mean = ws_f[ACC_OFF + layer] / Ns[layer];
            total += hard + n2mean;
        }
        __syncthreads();
    }
    if (tid == 0) out[0] = total;
}

extern "C" void kernel_launch(void* const* d_in, const int* in_sizes, int n_in,
                              void* d_out, int out_size, void* d_ws, size_t ws_size,
                              hipStream_t stream)
{
    const float* t0 = (const float*)d_in[0];
    const float* s0 = (const float*)d_in[1];
    const float* n0 = (const float*)d_in[2];
    const float* t1 = (const float*)d_in[3];
    const float* s1 = (const float*)d_in[4];
    const float* n1 = (const float*)d_in[5];
    const float* t2 = (const float*)d_in[6];
    const float* s2 = (const float*)d_in[7];
    const float* n2 = (const float*)d_in[8];

    // zero per-layer histograms + accumulators (ws is NOT re-poisoned between replays)
    hipMemsetAsync(d_ws, 0, (size_t)(ACC_OFF + 8) * 4, stream);

    stfpm_main<<<4480, 256, 0, stream>>>(t0, s0, n0, t1, s1, n1, t2, s2, n2,
                                         (unsigned int*)d_ws, (float*)d_ws);
    stfpm_finalize<<<1, 256, 0, stream>>>((const unsigned int*)d_ws,
                                          (const float*)d_ws, (float*)d_out);
}